// Round 4
// baseline (229.730 us; speedup 1.0000x reference)
//
#include <hip/hip_runtime.h>

// WideModel: 8 hashed multi-hot features + sparse linear combine.
// Strategy R3: one WAVE per ROW, all 8 features batched in the wave.
//  - 8 coalesced feature loads issued up front (overlapped vmem)
//  - dedupe via 8 wave-private 128-slot LDS hash sets; first CAS round for
//    all 8 features issued back-to-back (overlapped LDS atomic latency),
//    short straggler loops resolve collisions (~5/35 lanes)
//  - 8 independent W gathers, one shfl reduce, one plain store (no global
//    atomics, no init kernel, no __syncthreads)

constexpr int B = 16384;
constexpr int L = 50;
constexpr int SLOTS = 128;   // per feature; ~35 inserts -> short probes

struct KArgs {
    const int*   x[8];
    const float* w[8];
    const float* bias;
    float*       out;
};

__global__ __launch_bounds__(256) void wide_row_kernel(KArgs a) {
    __shared__ unsigned tbl[4][8][SLOTS];    // 4 waves x 8 feats x 128 x 4B = 16 KB

    const int wave = threadIdx.x >> 6;
    const int lane = threadIdx.x & 63;
    const int row  = (blockIdx.x << 2) | wave;

    // ---- issue all 8 feature loads up front (coalesced 200 B segments) ----
    int v[8];
    #pragma unroll
    for (int f = 0; f < 8; ++f)
        v[f] = (lane < L) ? a.x[f][row * L + lane] : -1;

    // ---- zero this wave's tables: 4 KB = 64 lanes x 4 x b128 ----
    {
        uint4* t4 = reinterpret_cast<uint4*>(&tbl[wave][0][0]);
        const uint4 z = {0u, 0u, 0u, 0u};
        #pragma unroll
        for (int i = 0; i < 4; ++i) t4[lane + 64 * i] = z;
    }
    // order zero-stores before CAS probes (same-wave LDS ops; no barrier needed)
    asm volatile("s_waitcnt lgkmcnt(0)" ::: "memory");

    // ---- hash all 8 (compile-time magic-mul mod) ----
    unsigned bin[8], h[8], key[8];
    bool pend[8], keep[8];
    #pragma unroll
    for (int f = 0; f < 8; ++f) {
        const bool valid = (v[f] >= 0);
        bin[f]  = (f < 6) ? ((unsigned)v[f] % 100000u)
                          : ((unsigned)v[f] % 1000000u);
        key[f]  = bin[f] + 1u;                      // 0 = empty sentinel
        h[f]    = (bin[f] * 2654435761u) >> 25;     // top 7 bits -> [0,128)
        pend[f] = valid;
        keep[f] = false;
    }

    // ---- CAS round 0: all 8 features issued back-to-back (overlapped) ----
    unsigned c0[8];
    #pragma unroll
    for (int f = 0; f < 8; ++f)
        if (pend[f]) c0[f] = atomicCAS(&tbl[wave][f][h[f]], 0u, key[f]);

    #pragma unroll
    for (int f = 0; f < 8; ++f) {
        if (pend[f]) {
            if (c0[f] == 0u)            { keep[f] = true;  pend[f] = false; }
            else if (c0[f] == key[f])   { pend[f] = false; }
            else                        { h[f] = (h[f] + 1) & (SLOTS - 1); }
        }
    }

    // ---- straggler rounds (rare: ~5/35 lanes per feature) ----
    #pragma unroll
    for (int f = 0; f < 8; ++f) {
        while (pend[f]) {
            const unsigned cur = atomicCAS(&tbl[wave][f][h[f]], 0u, key[f]);
            if (cur == 0u)          { keep[f] = true;  pend[f] = false; }
            else if (cur == key[f]) { pend[f] = false; }
            else                    { h[f] = (h[f] + 1) & (SLOTS - 1); }
        }
    }

    // ---- gathers: 8 independent predicated loads, then accumulate ----
    float wv[8];
    #pragma unroll
    for (int f = 0; f < 8; ++f)
        wv[f] = keep[f] ? a.w[f][bin[f]] : 0.0f;

    float acc = 0.0f;
    #pragma unroll
    for (int f = 0; f < 8; ++f) acc += wv[f];

    // ---- wave sum + single store ----
    #pragma unroll
    for (int off = 32; off; off >>= 1)
        acc += __shfl_xor(acc, off);

    if (lane == 0) a.out[row] = acc + a.bias[0];
}

extern "C" void kernel_launch(void* const* d_in, const int* in_sizes, int n_in,
                              void* d_out, int out_size, void* d_ws, size_t ws_size,
                              hipStream_t stream) {
    KArgs a;
    for (int i = 0; i < 8; ++i) a.x[i] = (const int*)d_in[i];
    for (int i = 0; i < 8; ++i) a.w[i] = (const float*)d_in[8 + i];
    a.bias = (const float*)d_in[16];
    a.out  = (float*)d_out;

    wide_row_kernel<<<B / 4, 256, 0, stream>>>(a);
}

// Round 5
// 39.016 us; speedup vs baseline: 5.8881x; 5.8881x over previous
//
#include <hip/hip_runtime.h>

// WideModel: 8 hashed multi-hot features + sparse linear combine.
// Strategy R4: one WAVE per row (R0 structure), dedupe via 64-lane BITONIC
// sorting network across lanes. xor-1/xor-2 exchange steps use DPP quad_perm
// (pure VALU, no LDS pipe); xor-4/8/16/32 use __shfl_xor. Pads (-1) map to
// 0xFFFFFFFF and sink to the top lanes. Dedupe = one shfl_up neighbor compare.
// No LDS tables, no atomics, one plain store per row.

constexpr int B = 16384;
constexpr int L = 50;

struct KArgs {
    const int*   x[8];
    const float* w[8];
    const float* bias;
    float*       out;
};

// DPP quad_perm lane swaps (VALU-only cross-lane for xor 1 / xor 2)
__device__ __forceinline__ unsigned dpp_xor1(unsigned v) {
    // quad_perm [1,0,3,2] = 0xB1
    return (unsigned)__builtin_amdgcn_update_dpp(0, (int)v, 0xB1, 0xF, 0xF, true);
}
__device__ __forceinline__ unsigned dpp_xor2(unsigned v) {
    // quad_perm [2,3,0,1] = 0x4E
    return (unsigned)__builtin_amdgcn_update_dpp(0, (int)v, 0x4E, 0xF, 0xF, true);
}

// one bitonic compare-exchange step; K = block size, J = partner distance.
// (lane&K), (lane&J) are compile-time-mask bit tests -> cheap lane math.
template <int K, int J>
__device__ __forceinline__ void bstep(unsigned& v, unsigned lane) {
    unsigned p;
    if constexpr (J == 1)      p = dpp_xor1(v);
    else if constexpr (J == 2) p = dpp_xor2(v);
    else                       p = (unsigned)__shfl_xor((int)v, J, 64);
    const bool up    = ((lane & (unsigned)K) == 0);  // ascending block?
    const bool lower = ((lane & (unsigned)J) == 0);  // lower element of pair?
    const unsigned mn = v < p ? v : p;
    const unsigned mx = v < p ? p : v;
    v = (up == lower) ? mn : mx;
}

__device__ __forceinline__ void bitonic64(unsigned& v, unsigned lane) {
    bstep<2, 1>(v, lane);
    bstep<4, 2>(v, lane);  bstep<4, 1>(v, lane);
    bstep<8, 4>(v, lane);  bstep<8, 2>(v, lane);  bstep<8, 1>(v, lane);
    bstep<16, 8>(v, lane); bstep<16, 4>(v, lane); bstep<16, 2>(v, lane);
    bstep<16, 1>(v, lane);
    bstep<32, 16>(v, lane); bstep<32, 8>(v, lane); bstep<32, 4>(v, lane);
    bstep<32, 2>(v, lane);  bstep<32, 1>(v, lane);
    bstep<64, 32>(v, lane); bstep<64, 16>(v, lane); bstep<64, 8>(v, lane);
    bstep<64, 4>(v, lane);  bstep<64, 2>(v, lane);  bstep<64, 1>(v, lane);
}

__global__ __launch_bounds__(256) void wide_sort_kernel(KArgs a) {
    const unsigned lane = threadIdx.x & 63u;
    const int row = (blockIdx.x << 2) | (int)(threadIdx.x >> 6);

    float acc = 0.0f;

    #pragma unroll
    for (int f = 0; f < 8; ++f) {
        // coalesced: lane i holds element i of the row (200 B segment)
        int v = (lane < L) ? a.x[f][row * L + lane] : -1;

        // compile-time magic-mul mod; pads -> 0xFFFFFFFF (sorts to top)
        unsigned bin = (f < 6) ? ((unsigned)v % 100000u)
                               : ((unsigned)v % 1000000u);
        bin = (v >= 0) ? bin : 0xFFFFFFFFu;

        bitonic64(bin, lane);

        // keep-first dedupe on the sorted sequence
        const unsigned prev = (unsigned)__shfl_up((int)bin, 1, 64);
        const unsigned BUCKET = (f < 6) ? 100000u : 1000000u;
        const bool keep = (bin < BUCKET) && (lane == 0 || bin != prev);

        if (keep) acc += a.w[f][bin];
    }

    // wave sum + single store (no atomics, no init kernel)
    #pragma unroll
    for (int off = 32; off; off >>= 1)
        acc += __shfl_xor(acc, off, 64);

    if (lane == 0) a.out[row] = acc + a.bias[0];
}

extern "C" void kernel_launch(void* const* d_in, const int* in_sizes, int n_in,
                              void* d_out, int out_size, void* d_ws, size_t ws_size,
                              hipStream_t stream) {
    KArgs a;
    for (int i = 0; i < 8; ++i) a.x[i] = (const int*)d_in[i];
    for (int i = 0; i < 8; ++i) a.w[i] = (const float*)d_in[8 + i];
    a.bias = (const float*)d_in[16];
    a.out  = (float*)d_out;

    wide_sort_kernel<<<B / 4, 256, 0, stream>>>(a);
}